// Round 3
// baseline (133.513 us; speedup 1.0000x reference)
//
#include <hip/hip_runtime.h>
#include <math.h>

// Problem constants: N=8, S=8192, C=1, K=1024, V=64
#define NS   65536
#define KK   1024
#define VV   64
#define WPB  4                // waves per block (256 threads)
#define SPW  32               // samples per wave (2 sample-tiles of 16)
#define SPB  (WPB * SPW)      // 128 samples per block
#define NB   (NS / SPB)       // 512 blocks
#define NT   64               // code tiles (16 codes each) = 1024 codes

// Output layout (flat, return order):
#define OUT0_OFF 0            // (8,8192,1,64) = 4,194,304
#define OUT1_OFF 4194304
#define OUT2_OFF 4259840
#define ENT_OFF  4325376      // entropy scalar; doubles as completion counter

// ws layout: [0,4K) hist u32; [4K,8K) cinit f32 (=1-0.5|e|^2); [8K,136K) frag-linear bf16 codebook

typedef __attribute__((ext_vector_type(8))) short bf16x8;
typedef __attribute__((ext_vector_type(4))) float f32x4;

__device__ __forceinline__ short f2bf(float f) {
    unsigned u = __float_as_uint(f);
    u = (u + 0x7fffu + ((u >> 16) & 1u)) >> 16;   // RNE
    return (short)u;
}

// prep: zero hist/entCnt, cinit = 1-0.5|e|^2, and FRAG-LINEAR bf16 codebook:
// tile T (codes 16T..16T+15): 2KB region, frag f (k 32f..32f+31) at f*1KB, within
// which lane l = quad*16+col holds code (16T+col), k-granule (4f+quad), 16B.
// -> vq_main loads a whole A-fragment with ONE fully-coalesced dwordx4 per lane.
__global__ void vq_prep(const float* __restrict__ emb, unsigned int* __restrict__ hist,
                        float* __restrict__ cinit, short* __restrict__ cb,
                        unsigned int* __restrict__ entCnt) {
    int t = blockIdx.x * blockDim.x + threadIdx.x;   // 1024 threads, one code each
    if (t == 0) entCnt[0] = 0u;
    if (t < KK) {
        hist[t] = 0u;
        const float4* e4 = (const float4*)(emb + (size_t)t * VV);
        const int T = t >> 4, cc = t & 15;
        float s = 0.f;
        union { short sh[8]; bf16x8 v; } pk;
        #pragma unroll
        for (int g = 0; g < 8; ++g) {
            float4 f0 = e4[2 * g], f1 = e4[2 * g + 1];
            s = fmaf(f0.x, f0.x, s); s = fmaf(f0.y, f0.y, s);
            s = fmaf(f0.z, f0.z, s); s = fmaf(f0.w, f0.w, s);
            s = fmaf(f1.x, f1.x, s); s = fmaf(f1.y, f1.y, s);
            s = fmaf(f1.z, f1.z, s); s = fmaf(f1.w, f1.w, s);
            pk.sh[0] = f2bf(f0.x); pk.sh[1] = f2bf(f0.y);
            pk.sh[2] = f2bf(f0.z); pk.sh[3] = f2bf(f0.w);
            pk.sh[4] = f2bf(f1.x); pk.sh[5] = f2bf(f1.y);
            pk.sh[6] = f2bf(f1.z); pk.sh[7] = f2bf(f1.w);
            // frag-linear slot: tile T*1024 shorts, frag (g>>2)*512, lane ((g&3)*16+cc)*8
            short* dst = cb + (size_t)T * 1024 + (g >> 2) * 512 + ((g & 3) * 16 + cc) * 8;
            *(bf16x8*)dst = pk.v;
        }
        cinit[t] = 1.0f - 0.5f * s;   // MFMA C-init; keeps scores in (0.85,1.15)
    }
}

// ZERO-LDS design: samples in registers (B-frags), codes streamed from L2 (A-frags).
// No barriers, no inter-wave coupling until the trivial tail. 2048 independent waves.
__global__ __launch_bounds__(256, 4) void vq_main(
    const float* __restrict__ x, const float* __restrict__ emb,
    const float* __restrict__ cinit, const short* __restrict__ cb,
    unsigned int* __restrict__ hist,
    float* __restrict__ out0, float* __restrict__ out1, float* __restrict__ out2,
    float* __restrict__ entOut)
{
    __shared__ float    sPart[WPB];   // entropy tail only (20 B LDS total)
    __shared__ unsigned sLast;

    const int tid  = threadIdx.x;
    const int lane = tid & 63;
    const int wv   = tid >> 6;        // 0..3
    const int col  = lane & 15;       // sample-within-tile (D col) / code-within-tile (A row)
    const int quad = lane >> 4;       // k-granule group / D row group
    const int samp0w = blockIdx.x * SPB + wv * SPW;   // this wave's 32 samples

    // ---- build B-frags from x (coalesced 64B-segment loads) + fp32 |x|^2 ----
    // b[st][hf]: sample st*16+col, k = hf*32 + quad*8 .. +7   (verified frag layout)
    bf16x8 b00, b01, b10, b11;
    float xn0, xn1;
    {
        const float* xw = x + (size_t)samp0w * VV;
        #pragma unroll
        for (int st = 0; st < 2; ++st) {
            float s = 0.f;
            bf16x8 vlo, vhi;
            #pragma unroll
            for (int hf = 0; hf < 2; ++hf) {
                const float* xp = xw + (st * 16 + col) * VV + hf * 32 + quad * 8;
                float4 p0 = *(const float4*)(xp);
                float4 p1 = *(const float4*)(xp + 4);
                bf16x8 v;
                v[0]=f2bf(p0.x); v[1]=f2bf(p0.y); v[2]=f2bf(p0.z); v[3]=f2bf(p0.w);
                v[4]=f2bf(p1.x); v[5]=f2bf(p1.y); v[6]=f2bf(p1.z); v[7]=f2bf(p1.w);
                s=fmaf(p0.x,p0.x,s); s=fmaf(p0.y,p0.y,s); s=fmaf(p0.z,p0.z,s); s=fmaf(p0.w,p0.w,s);
                s=fmaf(p1.x,p1.x,s); s=fmaf(p1.y,p1.y,s); s=fmaf(p1.z,p1.z,s); s=fmaf(p1.w,p1.w,s);
                if (hf == 0) vlo = v; else vhi = v;
            }
            // reduce |x|^2 over the 4 k-quads -> every lane holds it
            s += __shfl_xor(s, 16, 64);
            s += __shfl_xor(s, 32, 64);
            if (st == 0) { b00 = vlo; b01 = vhi; xn0 = s; }
            else         { b10 = vlo; b11 = vhi; xn1 = s; }
        }
    }

    // ---- stream all 64 code tiles from L2; packed max: score|22b . invcode|10b ----
    unsigned pm0 = 0u, pm1 = 0u;
    const char* cbl = (const char*)cb + lane * 16;
    const unsigned tagq = 1023u - (unsigned)(quad * 4);   // tag for r=0 of tile 0

    #pragma unroll 8
    for (int T = 0; T < NT; ++T) {
        bf16x8 A0 = *(const bf16x8*)(cbl + T * 2048);          // codes, k 0..31
        bf16x8 A1 = *(const bf16x8*)(cbl + T * 2048 + 1024);   // codes, k 32..63
        f32x4  cv = *(const f32x4*)(cinit + T * 16 + quad * 4);
        const unsigned tg = tagq - (unsigned)(T * 16);
        // D[row = code quad*4+r][col = sample]
        f32x4 a0 = __builtin_amdgcn_mfma_f32_16x16x32_bf16(A0, b00, cv, 0, 0, 0);
        a0       = __builtin_amdgcn_mfma_f32_16x16x32_bf16(A1, b01, a0, 0, 0, 0);
        f32x4 a1 = __builtin_amdgcn_mfma_f32_16x16x32_bf16(A0, b10, cv, 0, 0, 0);
        a1       = __builtin_amdgcn_mfma_f32_16x16x32_bf16(A1, b11, a1, 0, 0, 0);
        unsigned u0 = (__float_as_uint(a0[0]) & 0xFFFFFC00u) | tg;
        unsigned u1 = (__float_as_uint(a0[1]) & 0xFFFFFC00u) | (tg - 1u);
        unsigned u2 = (__float_as_uint(a0[2]) & 0xFFFFFC00u) | (tg - 2u);
        unsigned u3 = (__float_as_uint(a0[3]) & 0xFFFFFC00u) | (tg - 3u);
        unsigned m0 = u0 > u1 ? u0 : u1, m1 = u2 > u3 ? u2 : u3;
        unsigned mm = m0 > m1 ? m0 : m1;
        pm0 = pm0 > mm ? pm0 : mm;
        u0 = (__float_as_uint(a1[0]) & 0xFFFFFC00u) | tg;
        u1 = (__float_as_uint(a1[1]) & 0xFFFFFC00u) | (tg - 1u);
        u2 = (__float_as_uint(a1[2]) & 0xFFFFFC00u) | (tg - 2u);
        u3 = (__float_as_uint(a1[3]) & 0xFFFFFC00u) | (tg - 3u);
        m0 = u0 > u1 ? u0 : u1; m1 = u2 > u3 ? u2 : u3;
        mm = m0 > m1 ? m0 : m1;
        pm1 = pm1 > mm ? pm1 : mm;
    }

    // ---- in-wave argmin finish: butterfly over the quad dim (rows) ----
    {
        unsigned o;
        o = (unsigned)__shfl_xor((int)pm0, 16, 64); pm0 = o > pm0 ? o : pm0;
        o = (unsigned)__shfl_xor((int)pm0, 32, 64); pm0 = o > pm0 ? o : pm0;
        o = (unsigned)__shfl_xor((int)pm1, 16, 64); pm1 = o > pm1 ? o : pm1;
        o = (unsigned)__shfl_xor((int)pm1, 32, 64); pm1 = o > pm1 ? o : pm1;
    }   // now every lane holds the best for samples (0*16+col) and (1*16+col)

    // ---- out1/out2/hist: quad 0 covers sample-tile 0, quad 1 covers tile 1 ----
    if (quad < 2) {
        const unsigned p = quad ? pm1 : pm0;
        const float    xnv = quad ? xn1 : xn0;
        const int   code = 1023 - (int)(p & 1023u);
        const float sf   = __uint_as_float(p & 0xFFFFFC00u);
        const float d    = fmaf(-2.f, sf - 1.0f, xnv);   // sf-1 exact (Sterbenz)
        const int n = samp0w + quad * 16 + col;
        out1[n] = d;
        out2[n] = d;
        atomicAdd(&hist[code], 1u);
    }

    // ---- out0: 16-lane groups write one full sample row (256B contiguous) ----
    {
        float4* dstW = (float4*)(out0 + (size_t)samp0w * VV);   // 512 float4 per wave
        #pragma unroll
        for (int i = 0; i < 8; ++i) {
            const int idx = i * 64 + lane;
            const int sl  = idx >> 4;           // sample 0..31 (uniform per 16-lane group)
            const int c   = sl & 15;
            unsigned v0 = (unsigned)__shfl((int)pm0, c, 64);
            unsigned v1 = (unsigned)__shfl((int)pm1, c, 64);
            unsigned p  = (sl & 16) ? v1 : v0;
            const int code = 1023 - (int)(p & 1023u);
            dstW[idx] = *((const float4*)(emb + (size_t)code * VV) + (idx & 15));
        }
    }

    // ---- completion counter + fused entropy in the last block ----
    __syncthreads();   // this block's hist atomics drained (vmcnt(0) before barrier)
    unsigned int* entCnt = (unsigned int*)entOut;
    if (tid == 0)
        sLast = (__hip_atomic_fetch_add(entCnt, 1u, __ATOMIC_ACQ_REL,
                                        __HIP_MEMORY_SCOPE_AGENT) == (NB - 1)) ? 1u : 0u;
    __syncthreads();
    if (sLast) {
        float e = 0.f;
        #pragma unroll
        for (int i = 0; i < 4; ++i) {
            unsigned c = __hip_atomic_load(&hist[i * 256 + tid], __ATOMIC_RELAXED,
                                           __HIP_MEMORY_SCOPE_AGENT);
            if (c) { float pr = (float)c * (1.0f / (float)NS); e -= pr * logf(pr); }
        }
        #pragma unroll
        for (int off = 32; off > 0; off >>= 1) e += __shfl_down(e, off, 64);
        if (lane == 0) sPart[wv] = e;
        __syncthreads();
        if (tid == 0) entOut[0] = sPart[0] + sPart[1] + sPart[2] + sPart[3];
    }
}

extern "C" void kernel_launch(void* const* d_in, const int* in_sizes, int n_in,
                              void* d_out, int out_size, void* d_ws, size_t ws_size,
                              hipStream_t stream) {
    const float* x   = (const float*)d_in[0];   // (8,8192,1,64) fp32
    const float* emb = (const float*)d_in[1];   // (1,1024,64) fp32
    float* out = (float*)d_out;
    unsigned int* hist  = (unsigned int*)d_ws;
    float*        cinit = (float*)((char*)d_ws + 4096);
    short*        cb    = (short*)((char*)d_ws + 8192);   // frag-linear bf16 codebook, 128 KB

    vq_prep<<<4, 256, 0, stream>>>(emb, hist, cinit, cb, (unsigned int*)(out + ENT_OFF));
    vq_main<<<NB, 256, 0, stream>>>(x, emb, cinit, cb, hist,
                                    out + OUT0_OFF, out + OUT1_OFF, out + OUT2_OFF,
                                    out + ENT_OFF);
}

// Round 4
// 96.137 us; speedup vs baseline: 1.3888x; 1.3888x over previous
//
#include <hip/hip_runtime.h>
#include <math.h>

// Problem constants: N=8, S=8192, C=1, K=1024, V=64
#define NS   65536
#define KK   1024
#define VV   64
#define SPB  128              // samples per block
#define NB   (NS / SPB)       // 512 blocks -> 2 blocks/CU resident
#define NW   8                // waves per block (512 threads)
#define TPW  4                // code tiles per wave per pass (64 codes)
#define NPASS 2               // 8 waves x 4 tiles x 2 passes = 64 tiles = 1024 codes

// Output layout (flat, return order):
#define OUT0_OFF 0            // (8,8192,1,64) = 4,194,304
#define OUT1_OFF 4194304
#define OUT2_OFF 4259840
#define ENT_OFF  4325376      // entropy scalar; doubles as completion counter

// ws layout: [0,4K) hist u32; [4K,8K) cinit f32 (=1-0.5|e|^2); [8K,136K) frag-linear bf16 codebook

typedef __attribute__((ext_vector_type(8))) short bf16x8;
typedef __attribute__((ext_vector_type(4))) float f32x4;

__device__ __forceinline__ short f2bf(float f) {
    unsigned u = __float_as_uint(f);
    u = (u + 0x7fffu + ((u >> 16) & 1u)) >> 16;   // RNE
    return (short)u;
}

// prep: zero hist/entCnt, cinit = 1-0.5|e|^2, and FRAG-LINEAR bf16 codebook:
// tile T (codes 16T..16T+15), frag f (k-granules 4f..4f+3): 1KB region where
// lane l = quad*16+col holds code (16T+col), granule (4f+quad), 16B each.
// -> vq_main loads a whole A-fragment with ONE fully-coalesced dwordx4 per lane.
__global__ void vq_prep(const float* __restrict__ emb, unsigned int* __restrict__ hist,
                        float* __restrict__ cinit, short* __restrict__ cb,
                        unsigned int* __restrict__ entCnt) {
    int t = blockIdx.x * blockDim.x + threadIdx.x;   // 1024 threads, one code each
    if (t == 0) entCnt[0] = 0u;
    if (t < KK) {
        hist[t] = 0u;
        const float4* e4 = (const float4*)(emb + (size_t)t * VV);
        const int T = t >> 4, cc = t & 15;
        float s = 0.f;
        union { short sh[8]; bf16x8 v; } pk;
        #pragma unroll
        for (int g = 0; g < 8; ++g) {
            float4 f0 = e4[2 * g], f1 = e4[2 * g + 1];
            s = fmaf(f0.x, f0.x, s); s = fmaf(f0.y, f0.y, s);
            s = fmaf(f0.z, f0.z, s); s = fmaf(f0.w, f0.w, s);
            s = fmaf(f1.x, f1.x, s); s = fmaf(f1.y, f1.y, s);
            s = fmaf(f1.z, f1.z, s); s = fmaf(f1.w, f1.w, s);
            pk.sh[0] = f2bf(f0.x); pk.sh[1] = f2bf(f0.y);
            pk.sh[2] = f2bf(f0.z); pk.sh[3] = f2bf(f0.w);
            pk.sh[4] = f2bf(f1.x); pk.sh[5] = f2bf(f1.y);
            pk.sh[6] = f2bf(f1.z); pk.sh[7] = f2bf(f1.w);
            // frag-linear slot: tile T*1024 shorts, frag (g>>2)*512, lane ((g&3)*16+cc)*8
            short* dst = cb + (size_t)T * 1024 + (g >> 2) * 512 + ((g & 3) * 16 + cc) * 8;
            *(bf16x8*)dst = pk.v;
        }
        cinit[t] = 1.0f - 0.5f * s;   // MFMA C-init; keeps scores in (0.85,1.15)
    }
}

__global__ __launch_bounds__(512, 4) void vq_main(
    const float* __restrict__ x, const float* __restrict__ emb,
    const float* __restrict__ cinit, const short* __restrict__ cb,
    unsigned int* __restrict__ hist,
    float* __restrict__ out0, float* __restrict__ out1, float* __restrict__ out2,
    float* __restrict__ entOut)
{
    __shared__ __align__(16) char  sA[SPB * 128];     // 16 KB swizzled bf16 samples
    __shared__ float    sXn[SPB];
    __shared__ unsigned sRed[SPB][NW + 1];            // +1 pad -> <=2-way banks (free)
    __shared__ unsigned sPkF[SPB];
    __shared__ float    sPart[NW];
    __shared__ unsigned sLast;

    const int tid  = threadIdx.x;
    const int lane = tid & 63;
    const int wv   = tid >> 6;        // 0..7
    const int col  = lane & 15;       // B-operand n index (sample-within-tile)
    const int quad = lane >> 4;       // k-granule group
    const int samp0 = blockIdx.x * SPB;

    // ---- stage x -> sA (bf16, XOR-swizzled granules) + fp32 |x|^2 ----
    // thread t: sample s = t>>2, quarter q = t&3 -> 16 consecutive floats (64B, coalesced)
    {
        const int s = tid >> 2, q = tid & 3;
        const float4* xp = (const float4*)(x + (size_t)(samp0 + s) * VV + q * 16);
        float4 f0 = xp[0], f1 = xp[1], f2 = xp[2], f3 = xp[3];
        float sm = 0.f;
        sm=fmaf(f0.x,f0.x,sm); sm=fmaf(f0.y,f0.y,sm); sm=fmaf(f0.z,f0.z,sm); sm=fmaf(f0.w,f0.w,sm);
        sm=fmaf(f1.x,f1.x,sm); sm=fmaf(f1.y,f1.y,sm); sm=fmaf(f1.z,f1.z,sm); sm=fmaf(f1.w,f1.w,sm);
        sm=fmaf(f2.x,f2.x,sm); sm=fmaf(f2.y,f2.y,sm); sm=fmaf(f2.z,f2.z,sm); sm=fmaf(f2.w,f2.w,sm);
        sm=fmaf(f3.x,f3.x,sm); sm=fmaf(f3.y,f3.y,sm); sm=fmaf(f3.z,f3.z,sm); sm=fmaf(f3.w,f3.w,sm);
        union { short sh[8]; bf16x8 v; } pa, pb;
        pa.sh[0]=f2bf(f0.x); pa.sh[1]=f2bf(f0.y); pa.sh[2]=f2bf(f0.z); pa.sh[3]=f2bf(f0.w);
        pa.sh[4]=f2bf(f1.x); pa.sh[5]=f2bf(f1.y); pa.sh[6]=f2bf(f1.z); pa.sh[7]=f2bf(f1.w);
        pb.sh[0]=f2bf(f2.x); pb.sh[1]=f2bf(f2.y); pb.sh[2]=f2bf(f2.z); pb.sh[3]=f2bf(f2.w);
        pb.sh[4]=f2bf(f3.x); pb.sh[5]=f2bf(f3.y); pb.sh[6]=f2bf(f3.z); pb.sh[7]=f2bf(f3.w);
        short* base = (short*)(sA + s * 128);
        // granule g at swizzled slot g ^ (s&7): matches read swizzle below
        *(bf16x8*)(base + ((((2*q)    ) ^ (s & 7)) << 3)) = pa.v;
        *(bf16x8*)(base + ((((2*q) + 1) ^ (s & 7)) << 3)) = pb.v;
        sm += __shfl_xor(sm, 1, 64);
        sm += __shfl_xor(sm, 2, 64);
        if ((tid & 3) == 0) sXn[s] = sm;
    }

    // B-frag read offsets (verified conflict-free pattern: row*128 ^ granule swizzle)
    const int rb0 = col * 128 + (( quad      ^ (col & 7)) << 4);
    const int rb1 = col * 128 + (((4 + quad) ^ (col & 7)) << 4);

    // packed running maxima per m-tile: high 22 bits = score, low 10 = 1023-code
    unsigned pmv[8];
    #pragma unroll
    for (int j = 0; j < 8; ++j) pmv[j] = 0u;

    for (int p = 0; p < NPASS; ++p) {
        // ---- this wave's 64 codes -> registers (A-frags, cinit, inv tags) ----
        bf16x8   af0[TPW], af1[TPW];
        f32x4    cv[TPW];
        unsigned inv[TPW][4];
        const int Tb = p * 32 + wv * TPW;
        #pragma unroll
        for (int t = 0; t < TPW; ++t) {
            const char* cp = (const char*)cb + (size_t)(Tb + t) * 2048;
            af0[t] = *(const bf16x8*)(cp + lane * 16);          // k 0..31, fully coalesced
            af1[t] = *(const bf16x8*)(cp + 1024 + lane * 16);   // k 32..63
            cv[t]  = *(const f32x4*)(cinit + (Tb + t) * 16 + quad * 4);
            const unsigned ib = 1023u - (unsigned)((Tb + t) * 16 + quad * 4);
            inv[t][0] = ib; inv[t][1] = ib - 1; inv[t][2] = ib - 2; inv[t][3] = ib - 3;
        }
        if (p == 0) __syncthreads();   // sA/sXn ready; pass-0 frag loads overlapped staging

        // ---- barrier-free main loop: 8 sample tiles x 4 code tiles ----
        #pragma unroll
        for (int mt = 0; mt < 8; ++mt) {
            const char* Bp = sA + mt * 2048;
            bf16x8 b0 = *(const bf16x8*)(Bp + rb0);
            bf16x8 b1 = *(const bf16x8*)(Bp + rb1);
            #pragma unroll
            for (int t = 0; t < TPW; ++t) {
                f32x4 acc = __builtin_amdgcn_mfma_f32_16x16x32_bf16(af0[t], b0, cv[t], 0, 0, 0);
                acc       = __builtin_amdgcn_mfma_f32_16x16x32_bf16(af1[t], b1, acc,   0, 0, 0);
                // D: row = code (quad*4+r), col = sample  -> pack score|invcode
                unsigned u0 = (__float_as_uint(acc[0]) & 0xFFFFFC00u) | inv[t][0];
                unsigned u1 = (__float_as_uint(acc[1]) & 0xFFFFFC00u) | inv[t][1];
                unsigned u2 = (__float_as_uint(acc[2]) & 0xFFFFFC00u) | inv[t][2];
                unsigned u3 = (__float_as_uint(acc[3]) & 0xFFFFFC00u) | inv[t][3];
                unsigned m0 = u0 > u1 ? u0 : u1;
                unsigned m1 = u2 > u3 ? u2 : u3;
                unsigned mm = m0 > m1 ? m0 : m1;
                pmv[mt] = pmv[mt] > mm ? pmv[mt] : mm;
            }
        }
    }

    // ---- per-sample max over the quad dim (codes quad*4+r live in quad groups) ----
    #pragma unroll
    for (int j = 0; j < 8; ++j) {
        unsigned o;
        o = (unsigned)__shfl_xor((int)pmv[j], 16, 64); pmv[j] = o > pmv[j] ? o : pmv[j];
        o = (unsigned)__shfl_xor((int)pmv[j], 32, 64); pmv[j] = o > pmv[j] ? o : pmv[j];
    }
    // each quad writes samples quad*16+col and (quad+4)*16+col (static-index selects)
    {
        unsigned w0 = (quad & 1) ? pmv[1] : pmv[0];
        unsigned w1 = (quad & 1) ? pmv[3] : pmv[2];
        unsigned lo = (quad & 2) ? w1 : w0;            // pmv[quad]
        unsigned w2 = (quad & 1) ? pmv[5] : pmv[4];
        unsigned w3 = (quad & 1) ? pmv[7] : pmv[6];
        unsigned hi = (quad & 2) ? w3 : w2;            // pmv[quad+4]
        sRed[quad * 16 + col][wv]       = lo;
        sRed[(quad + 4) * 16 + col][wv] = hi;
    }
    __syncthreads();

    // ---- final per-sample reduce over 8 waves + out1/out2/hist ----
    if (tid < SPB) {
        unsigned pbest = sRed[tid][0];
        #pragma unroll
        for (int w = 1; w < NW; ++w) {
            unsigned o = sRed[tid][w];
            pbest = o > pbest ? o : pbest;
        }
        sPkF[tid] = pbest;
        int   code = 1023 - (int)(pbest & 1023u);
        float sf   = __uint_as_float(pbest & 0xFFFFFC00u);
        float d    = fmaf(-2.f, sf - 1.0f, sXn[tid]);   // sf-1 exact (Sterbenz)
        int n = samp0 + tid;
        out1[n] = d;
        out2[n] = d;
        atomicAdd(&hist[code], 1u);
    }
    __syncthreads();

    // ---- out0 gather: lane-contiguous float4 stores (1KB/wave/instr) ----
    {
        float4* dstB = (float4*)(out0 + (size_t)samp0 * VV);   // 2048 float4s per block
        #pragma unroll
        for (int i = 0; i < 4; ++i) {
            const int idx  = i * 512 + tid;
            const int smp  = idx >> 4;
            const int part = idx & 15;
            const int code = 1023 - (int)(sPkF[smp] & 1023u);
            dstB[idx] = *((const float4*)(emb + (size_t)code * VV) + part);
        }
    }

    // ---- completion counter + fused entropy in the last block ----
    // NOTE: plain atomicAdd only (device-scope RMW at the coherence point).
    // NO agent-scope acq_rel fences here: those emit per-block L2 writeback/
    // invalidate, evicting the shared codebook/x lines for all sibling blocks
    // on the XCD (r1-r3 regression suspect). r0's fence-free tail passed.
    __syncthreads();   // this block's hist atomics drained (vmcnt(0) before barrier)
    unsigned int* entCnt = (unsigned int*)entOut;
    if (tid == 0) sLast = (atomicAdd(entCnt, 1u) == (NB - 1)) ? 1u : 0u;
    __syncthreads();
    if (sLast) {
        float e = 0.f;
        #pragma unroll
        for (int i = 0; i < 2; ++i) {
            unsigned c = atomicAdd(&hist[i * 512 + tid], 0u);   // coherent-point read
            if (c) { float pr = (float)c * (1.0f / (float)NS); e -= pr * logf(pr); }
        }
        #pragma unroll
        for (int off = 32; off > 0; off >>= 1) e += __shfl_down(e, off, 64);
        if (lane == 0) sPart[wv] = e;
        __syncthreads();
        if (tid == 0) {
            float s = 0.f;
            #pragma unroll
            for (int i = 0; i < NW; ++i) s += sPart[i];
            entOut[0] = s;
        }
    }
}

extern "C" void kernel_launch(void* const* d_in, const int* in_sizes, int n_in,
                              void* d_out, int out_size, void* d_ws, size_t ws_size,
                              hipStream_t stream) {
    const float* x   = (const float*)d_in[0];   // (8,8192,1,64) fp32
    const float* emb = (const float*)d_in[1];   // (1,1024,64) fp32
    float* out = (float*)d_out;
    unsigned int* hist  = (unsigned int*)d_ws;
    float*        cinit = (float*)((char*)d_ws + 4096);
    short*        cb    = (short*)((char*)d_ws + 8192);   // frag-linear bf16 codebook, 128 KB

    vq_prep<<<4, 256, 0, stream>>>(emb, hist, cinit, cb, (unsigned int*)(out + ENT_OFF));
    vq_main<<<NB, 512, 0, stream>>>(x, emb, cinit, cb, hist,
                                    out + OUT0_OFF, out + OUT1_OFF, out + OUT2_OFF,
                                    out + ENT_OFF);
}